// Round 5
// baseline (28.585 us; speedup 1.0000x reference)
//
#include <hip/hip_runtime.h>

// JPEG differentiable codec, fused. Identity: IDCT(DCT(p)+nf) = p + IDCT(nf);
// only the quantization NOISE is IDCT'd: nf = 0.125*eps*table*AA*rv.
// Round-4: streaming restructure. 128x32-px tile / 256 threads / 16 px per
// thread in 2 passes (8 px = one u-row each, yv kept in regs). Wave-level
// global accesses are 512 B contiguous chunks. Output uses NON-TEMPORAL
// stores so the write stream doesn't evict inputs from L3 (inputs then stay
// L3-resident across graph replays -> HBM ~= write traffic only).
// LDS: stage-1 buffers use x-stride 9 words + per-bj pad (all accesses
// <=2-way by construction, scalar b32 where alignment requires); 2 barriers.
//
// Index map (validated rounds 0-3): img[b,i,j,c] = pixel_inp[b,c,j,i];
// Y block n = (i/8)*32 + j/8, in-block offset = (i%8)*8 + (j%8); ref tables
// are .T so table[x][y] = std[y][x]; chroma at (ci,cj)=(i/2,j/2),
// n_c = (ci/8)*16 + cj/8.

__constant__ float YBT[64] = {   // YBT[x*8+y] = std_luma[y][x]
  16,12,14,14,18,24,49,72,
  11,12,13,17,22,35,64,92,
  10,14,16,22,37,55,78,95,
  16,19,24,29,56,64,87,98,
  24,26,40,51,68,81,103,112,
  40,58,57,87,109,104,121,100,
  51,60,69,80,103,113,120,103,
  61,55,56,62,77,92,101,99};

__constant__ float CBTc[64] = {  // symmetric -> transpose = itself
  17,18,24,47,99,99,99,99,
  18,21,26,66,99,99,99,99,
  24,26,56,99,99,99,99,99,
  47,66,99,99,99,99,99,99,
  99,99,99,99,99,99,99,99,
  99,99,99,99,99,99,99,99,
  99,99,99,99,99,99,99,99,
  99,99,99,99,99,99,99,99};

typedef float f4v __attribute__((ext_vector_type(4)));

// o[u] = sum_k t[k] * cos((2u+1)*k*pi/16)
__device__ __forceinline__ void idct8(const float* __restrict__ t,
                                      float* __restrict__ o) {
    const float r  = 0.70710678118654752f;
    const float a  = 0.92387953251128674f;
    const float bq = 0.38268343236508977f;
    const float c1 = 0.98078528040323044f;
    const float c3 = 0.83146961230254524f;
    const float c5 = 0.55557023301960222f;
    const float c7 = 0.19509032201612827f;
    const float p  = fmaf(r,  t[4], t[0]);
    const float m  = fmaf(-r, t[4], t[0]);
    const float q  = fmaf(a,  t[2],  bq*t[6]);
    const float s  = fmaf(bq, t[2],  -a*t[6]);
    const float E0 = p + q, E3 = p - q, E1 = m + s, E2 = m - s;
    const float O0 = fmaf(c1,t[1], fmaf( c3,t[3], fmaf( c5,t[5],  c7*t[7])));
    const float O1 = fmaf(c3,t[1], fmaf(-c7,t[3], fmaf(-c1,t[5], -c5*t[7])));
    const float O2 = fmaf(c5,t[1], fmaf(-c1,t[3], fmaf( c7,t[5],  c3*t[7])));
    const float O3 = fmaf(c7,t[1], fmaf(-c5,t[3], fmaf( c3,t[5], -c1*t[7])));
    o[0]=E0+O0; o[7]=E0-O0; o[1]=E1+O1; o[6]=E1-O1;
    o[2]=E2+O2; o[5]=E2-O2; o[3]=E3+O3; o[4]=E3-O3;
}

// sY: [bj][bi][x][v]  offset = bj*1220 + bi*76 + x*9 + v   (scalar access)
// sC: [qc][x][v]      offset = qc*76 + x*9 + v
// pool: [ch][cj][ci]  offset = ch*1088 + cj*68 + ci        (16B-aligned f4)

__global__ __launch_bounds__(256, 4) void jpeg_kernel(
    const float* __restrict__ pix,   // [B,3,256,256]
    const float* __restrict__ rvy,   // [B,1024,8,8]
    const float* __restrict__ rvcb,  // [B,256,8,8]
    const float* __restrict__ rvcr,  // [B,256,8,8]
    const float* __restrict__ epsv,  // [B]
    float* __restrict__ out)         // [B,3,256,256]
{
    __shared__ float sY[4872];
    __shared__ float sC[2432];
    __shared__ float pool[2176];

    const int tid = threadIdx.x;
    const int b   = blockIdx.y;
    const int th  = blockIdx.x >> 3;   // i-tile (0..1), 128 px
    const int tv  = blockIdx.x & 7;    // j-tile (0..7), 32 px

    const float eps8 = epsv[b] * 0.125f;
    const float RT   = 0.70710678118654752f;

    // ================= load phase (issue everything early) =================
    const int xc = tid & 7;
    const int qa = tid >> 3;                 // Y task A: q=qa; B: q=qa+32
    const int biA = qa >> 2, bjA = qa & 3;   // bj-fast -> 1KB global chunks
    const size_t rvyb = (size_t)b * 65536;
    const float* rpA = rvy + rvyb + (size_t)(((th*16 + biA    )*32) + tv*4 + bjA)*64 + xc*8;
    const float* rpB = rvy + rvyb + (size_t)(((th*16 + biA + 8)*32) + tv*4 + bjA)*64 + xc*8;
    const float4 ya0 = *(const float4*)rpA, ya1 = *(const float4*)(rpA + 4);
    const float4 yb0 = *(const float4*)rpB, yb1 = *(const float4*)(rpB + 4);

    const int qc  = tid >> 3;                // chroma task (1 per thread)
    const int chq = qc >> 4, cbi = (qc >> 1) & 7, cbj = qc & 1;
    const float* __restrict__ rvc = chq ? rvcr : rvcb;
    const float* rpC = rvc + (size_t)b*16384 + (size_t)((th*8 + cbi)*16 + tv*2 + cbj)*64 + xc*8;
    const float4 cc0 = *(const float4*)rpC, cc1 = *(const float4*)(rpC + 4);

    const float4 tY0 = *(const float4*)&YBT[xc*8],  tY1 = *(const float4*)&YBT[xc*8 + 4];
    const float4 tC0 = *(const float4*)&CBTc[xc*8], tC1 = *(const float4*)&CBTc[xc*8 + 4];

    const int rloc = tid >> 4;               // row 0..15 (per pass)
    const int i08  = (tid & 15) * 8;
    const size_t pbase0 = (size_t)b*196608 + (size_t)(tv*32 + rloc)*256 + th*128 + i08;
    const size_t pbase1 = pbase0 + 4096;     // +16 rows
    const float4 pr0a = *(const float4*)(pix + pbase0);
    const float4 pr0b = *(const float4*)(pix + pbase0 + 4);
    const float4 pg0a = *(const float4*)(pix + pbase0 + 65536);
    const float4 pg0b = *(const float4*)(pix + pbase0 + 65540);
    const float4 pb0a = *(const float4*)(pix + pbase0 + 131072);
    const float4 pb0b = *(const float4*)(pix + pbase0 + 131076);

    // ================= stage 1: column IDCTs of scaled noise ===============
    const float aax = (xc == 0 ? RT : 1.0f) * eps8;
    {
        float t[8], o[8];
        t[0]=ya0.x*(tY0.x*aax*RT); t[1]=ya0.y*(tY0.y*aax);
        t[2]=ya0.z*(tY0.z*aax);    t[3]=ya0.w*(tY0.w*aax);
        t[4]=ya1.x*(tY1.x*aax);    t[5]=ya1.y*(tY1.y*aax);
        t[6]=ya1.z*(tY1.z*aax);    t[7]=ya1.w*(tY1.w*aax);
        idct8(t, o);
        float* w = &sY[bjA*1220 + biA*76 + xc*9];
        #pragma unroll
        for (int v = 0; v < 8; ++v) w[v] = o[v];
    }
    {
        float t[8], o[8];
        t[0]=yb0.x*(tY0.x*aax*RT); t[1]=yb0.y*(tY0.y*aax);
        t[2]=yb0.z*(tY0.z*aax);    t[3]=yb0.w*(tY0.w*aax);
        t[4]=yb1.x*(tY1.x*aax);    t[5]=yb1.y*(tY1.y*aax);
        t[6]=yb1.z*(tY1.z*aax);    t[7]=yb1.w*(tY1.w*aax);
        idct8(t, o);
        float* w = &sY[bjA*1220 + (biA + 8)*76 + xc*9];
        #pragma unroll
        for (int v = 0; v < 8; ++v) w[v] = o[v];
    }
    {
        float t[8], o[8];
        t[0]=cc0.x*(tC0.x*aax*RT); t[1]=cc0.y*(tC0.y*aax);
        t[2]=cc0.z*(tC0.z*aax);    t[3]=cc0.w*(tC0.w*aax);
        t[4]=cc1.x*(tC1.x*aax);    t[5]=cc1.y*(tC1.y*aax);
        t[6]=cc1.z*(tC1.z*aax);    t[7]=cc1.w*(tC1.w*aax);
        idct8(t, o);
        float* w = &sC[qc*76 + xc*9];
        #pragma unroll
        for (int v = 0; v < 8; ++v) w[v] = o[v];
    }

    // ================= pixel pass 1 loads, then YCC both passes ============
    const float4 pr1a = *(const float4*)(pix + pbase1);
    const float4 pr1b = *(const float4*)(pix + pbase1 + 4);
    const float4 pg1a = *(const float4*)(pix + pbase1 + 65536);
    const float4 pg1b = *(const float4*)(pix + pbase1 + 65540);
    const float4 pb1a = *(const float4*)(pix + pbase1 + 131072);
    const float4 pb1b = *(const float4*)(pix + pbase1 + 131076);

    float yva[8], yvb[8];
    {   // pass 0
        const float rr[8] = {pr0a.x,pr0a.y,pr0a.z,pr0a.w,pr0b.x,pr0b.y,pr0b.z,pr0b.w};
        const float gg[8] = {pg0a.x,pg0a.y,pg0a.z,pg0a.w,pg0b.x,pg0b.y,pg0b.z,pg0b.w};
        const float bb[8] = {pb0a.x,pb0a.y,pb0a.z,pb0a.w,pb0b.x,pb0b.y,pb0b.z,pb0b.w};
        float cbv[8], crv[8];
        #pragma unroll
        for (int c = 0; c < 8; ++c) {
            yva[c] = fmaf(0.299f, rr[c], fmaf(0.587f, gg[c], 0.114f*bb[c]));
            cbv[c] = fmaf(-0.168736f, rr[c], fmaf(-0.331264f, gg[c], 0.5f*bb[c]));
            crv[c] = fmaf(0.5f, rr[c], fmaf(-0.418688f, gg[c], -0.081312f*bb[c]));
        }
        float s0=cbv[0]+cbv[1], s1=cbv[2]+cbv[3], s2=cbv[4]+cbv[5], s3=cbv[6]+cbv[7];
        float u0=crv[0]+crv[1], u1=crv[2]+crv[3], u2=crv[4]+crv[5], u3=crv[6]+crv[7];
        s0 += __shfl_xor(s0,16); s1 += __shfl_xor(s1,16);
        s2 += __shfl_xor(s2,16); s3 += __shfl_xor(s3,16);
        u0 += __shfl_xor(u0,16); u1 += __shfl_xor(u1,16);
        u2 += __shfl_xor(u2,16); u3 += __shfl_xor(u3,16);
        if (!(tid & 16)) {
            float* pp = &pool[(tid >> 5)*68 + (tid & 15)*4];
            *(f4v*)pp          = (f4v){0.25f*s0, 0.25f*s1, 0.25f*s2, 0.25f*s3};
            *(f4v*)(pp + 1088) = (f4v){0.25f*u0, 0.25f*u1, 0.25f*u2, 0.25f*u3};
        }
    }
    {   // pass 1
        const float rr[8] = {pr1a.x,pr1a.y,pr1a.z,pr1a.w,pr1b.x,pr1b.y,pr1b.z,pr1b.w};
        const float gg[8] = {pg1a.x,pg1a.y,pg1a.z,pg1a.w,pg1b.x,pg1b.y,pg1b.z,pg1b.w};
        const float bb[8] = {pb1a.x,pb1a.y,pb1a.z,pb1a.w,pb1b.x,pb1b.y,pb1b.z,pb1b.w};
        float cbv[8], crv[8];
        #pragma unroll
        for (int c = 0; c < 8; ++c) {
            yvb[c] = fmaf(0.299f, rr[c], fmaf(0.587f, gg[c], 0.114f*bb[c]));
            cbv[c] = fmaf(-0.168736f, rr[c], fmaf(-0.331264f, gg[c], 0.5f*bb[c]));
            crv[c] = fmaf(0.5f, rr[c], fmaf(-0.418688f, gg[c], -0.081312f*bb[c]));
        }
        float s0=cbv[0]+cbv[1], s1=cbv[2]+cbv[3], s2=cbv[4]+cbv[5], s3=cbv[6]+cbv[7];
        float u0=crv[0]+crv[1], u1=crv[2]+crv[3], u2=crv[4]+crv[5], u3=crv[6]+crv[7];
        s0 += __shfl_xor(s0,16); s1 += __shfl_xor(s1,16);
        s2 += __shfl_xor(s2,16); s3 += __shfl_xor(s3,16);
        u0 += __shfl_xor(u0,16); u1 += __shfl_xor(u1,16);
        u2 += __shfl_xor(u2,16); u3 += __shfl_xor(u3,16);
        if (!(tid & 16)) {
            float* pp = &pool[(8 + (tid >> 5))*68 + (tid & 15)*4];
            *(f4v*)pp          = (f4v){0.25f*s0, 0.25f*s1, 0.25f*s2, 0.25f*s3};
            *(f4v*)(pp + 1088) = (f4v){0.25f*u0, 0.25f*u1, 0.25f*u2, 0.25f*u3};
        }
    }
    __syncthreads();   // A: sY, sC, pool(pooled) ready

    // ================= phase II: chroma row-IDCT, add into pool ============
    {
        const int q2 = tid >> 3, vc = tid & 7;
        const float* rs = &sC[q2*76 + vc];
        float t[8];
        #pragma unroll
        for (int x = 0; x < 8; ++x) t[x] = rs[x*9];
        float cn[8];
        idct8(t, cn);
        const int ch2 = q2 >> 4, cbi2 = (q2 >> 1) & 7, cbj2 = q2 & 1;
        float* pp = &pool[ch2*1088 + (cbj2*8 + vc)*68 + cbi2*8];
        f4v p0 = *(f4v*)pp, p1 = *(f4v*)(pp + 4);
        p0 += (f4v){cn[0], cn[1], cn[2], cn[3]};
        p1 += (f4v){cn[4], cn[5], cn[6], cn[7]};
        *(f4v*)pp       = p0;
        *(f4v*)(pp + 4) = p1;
    }
    __syncthreads();   // B: chroma-final pool ready

    // ================= phase III: Y row-IDCT + recombine + nt stores =======
    const int v3  = (tid >> 4) & 7;
    const int bi3 = tid & 15;
    #pragma unroll
    for (int p = 0; p < 2; ++p) {
        const float* ry = &sY[(2*p + (tid >> 7))*1220 + bi3*76 + v3];
        float t[8];
        #pragma unroll
        for (int x = 0; x < 8; ++x) t[x] = ry[x*9];
        float yn[8];
        idct8(t, yn);
        const float* pc = &pool[(p*8 + (tid >> 5))*68 + (tid & 15)*4];
        const f4v cbq = *(const f4v*)pc;
        const f4v crq = *(const f4v*)(pc + 1088);
        const float* yv = p ? yvb : yva;
        float R[8], G[8], Bl[8];
        #pragma unroll
        for (int c = 0; c < 8; ++c) {
            const float cb = cbq[c >> 1], cr = crq[c >> 1];
            const float yf = yv[c] + yn[c];
            float r_ = fmaf(1.402f, cr, yf);
            float g_ = fmaf(-0.344136f, cb, fmaf(-0.714136f, cr, yf));
            float b_ = fmaf(1.772f, cb, yf);
            R[c]  = fminf(fmaxf(r_, 0.0f), 255.0f);
            G[c]  = fminf(fmaxf(g_, 0.0f), 255.0f);
            Bl[c] = fminf(fmaxf(b_, 0.0f), 255.0f);
        }
        float* ob = (float*)out + (p ? pbase1 : pbase0);
        __builtin_nontemporal_store((f4v){R[0],R[1],R[2],R[3]},   (f4v*)(ob));
        __builtin_nontemporal_store((f4v){R[4],R[5],R[6],R[7]},   (f4v*)(ob + 4));
        __builtin_nontemporal_store((f4v){G[0],G[1],G[2],G[3]},   (f4v*)(ob + 65536));
        __builtin_nontemporal_store((f4v){G[4],G[5],G[6],G[7]},   (f4v*)(ob + 65540));
        __builtin_nontemporal_store((f4v){Bl[0],Bl[1],Bl[2],Bl[3]},(f4v*)(ob + 131072));
        __builtin_nontemporal_store((f4v){Bl[4],Bl[5],Bl[6],Bl[7]},(f4v*)(ob + 131076));
    }
}

extern "C" void kernel_launch(void* const* d_in, const int* in_sizes, int n_in,
                              void* d_out, int out_size, void* d_ws, size_t ws_size,
                              hipStream_t stream) {
    const float* pix  = (const float*)d_in[0];
    const float* rvy  = (const float*)d_in[1];
    const float* rvcb = (const float*)d_in[2];
    const float* rvcr = (const float*)d_in[3];
    const float* eps  = (const float*)d_in[4];
    const int B = in_sizes[4];           // epsilon: one per batch
    dim3 grid(16, B);                    // 2x8 tiles of 128x32 px, per batch
    jpeg_kernel<<<grid, 256, 0, stream>>>(pix, rvy, rvcb, rvcr, eps, (float*)d_out);
}

// Round 6
// 25.471 us; speedup vs baseline: 1.1223x; 1.1223x over previous
//
#include <hip/hip_runtime.h>

// JPEG differentiable codec, fused. Identity: IDCT(DCT(p)+nf) = p + IDCT(nf);
// only the quantization NOISE is IDCT'd: nf = 0.125*eps*table*AA*rv.
// Round-5: BARRIER-FREE wave-autonomous structure. Each wave owns a 16x16-px
// tile (4 Y blocks + 1 Cb + 1 Cr), with a private LDS slice; all stage
// hand-offs are wave-internal (lockstep wave64 + compiler lgkmcnt), so the
// kernel has ZERO __syncthreads -> waves de-phase and keep HBM continuously
// busy instead of load-burst/compute/store phase-locking at block barriers.
// Fast literal-constant 8-pt IDCT butterflies (validated r2-r4). 4 px/thread.
// __launch_bounds__(256,6): cap 80 VGPR -> 6 blocks/CU resident.
//
// Index map (validated rounds 0-4): img[b,i,j,c] = pixel_inp[b,c,j,i];
// Y block n = (i/8)*32 + j/8, in-block offset = (i%8)*8 + (j%8); ref tables
// are .T so table[x][y] = std[y][x]; chroma at (ci,cj)=(i/2,j/2),
// n_c = (ci/8)*16 + cj/8.
//
// Per-wave LDS slice (words, stride-engineered):
//   sY  @0    : [q:4][v:8 (stride12)][x:8]   = 416   (scalar writes 8q+12v+xc
//                                              -> 32 distinct banks, conflict-free)
//   sC  @416  : [ch:2][v:8 (stride12)][x:8]  = 208
//   ny  @624  : [j:16 (stride20)][i:16]      = 320   (f4 ops, <=2-way)
//   pool@944  : [ch:2 (stride96)][cj:8 (stride12)][ci:8] = 192
//   total 1136 words = 4.44 KB; x4 waves = 17.8 KB/block

__constant__ float YBT[64] = {   // YBT[x*8+y] = std_luma[y][x]
  16,12,14,14,18,24,49,72,
  11,12,13,17,22,35,64,92,
  10,14,16,22,37,55,78,95,
  16,19,24,29,56,64,87,98,
  24,26,40,51,68,81,103,112,
  40,58,57,87,109,104,121,100,
  51,60,69,80,103,113,120,103,
  61,55,56,62,77,92,101,99};

__constant__ float CBTc[64] = {  // symmetric -> transpose = itself
  17,18,24,47,99,99,99,99,
  18,21,26,66,99,99,99,99,
  24,26,56,99,99,99,99,99,
  47,66,99,99,99,99,99,99,
  99,99,99,99,99,99,99,99,
  99,99,99,99,99,99,99,99,
  99,99,99,99,99,99,99,99,
  99,99,99,99,99,99,99,99};

typedef float f4v __attribute__((ext_vector_type(4)));
typedef float f2v __attribute__((ext_vector_type(2)));

// o[u] = sum_k t[k] * cos((2u+1)*k*pi/16)
__device__ __forceinline__ void idct8(const float* __restrict__ t,
                                      float* __restrict__ o) {
    const float r  = 0.70710678118654752f;
    const float a  = 0.92387953251128674f;
    const float bq = 0.38268343236508977f;
    const float c1 = 0.98078528040323044f;
    const float c3 = 0.83146961230254524f;
    const float c5 = 0.55557023301960222f;
    const float c7 = 0.19509032201612827f;
    const float p  = fmaf(r,  t[4], t[0]);
    const float m  = fmaf(-r, t[4], t[0]);
    const float q  = fmaf(a,  t[2],  bq*t[6]);
    const float s  = fmaf(bq, t[2],  -a*t[6]);
    const float E0 = p + q, E3 = p - q, E1 = m + s, E2 = m - s;
    const float O0 = fmaf(c1,t[1], fmaf( c3,t[3], fmaf( c5,t[5],  c7*t[7])));
    const float O1 = fmaf(c3,t[1], fmaf(-c7,t[3], fmaf(-c1,t[5], -c5*t[7])));
    const float O2 = fmaf(c5,t[1], fmaf(-c1,t[3], fmaf( c7,t[5],  c3*t[7])));
    const float O3 = fmaf(c7,t[1], fmaf(-c5,t[3], fmaf( c3,t[5], -c1*t[7])));
    o[0]=E0+O0; o[7]=E0-O0; o[1]=E1+O1; o[6]=E1-O1;
    o[2]=E2+O2; o[5]=E2-O2; o[3]=E3+O3; o[4]=E3-O3;
}

__global__ __launch_bounds__(256, 6) void jpeg_kernel(
    const float* __restrict__ pix,   // [B,3,256,256]
    const float* __restrict__ rvy,   // [B,1024,8,8]
    const float* __restrict__ rvcb,  // [B,256,8,8]
    const float* __restrict__ rvcr,  // [B,256,8,8]
    const float* __restrict__ epsv,  // [B]
    float* __restrict__ out)         // [B,3,256,256]
{
    __shared__ __align__(16) float lds[4*1136];

    const int tid  = threadIdx.x;
    const int lane = tid & 63;
    const int wv   = tid >> 6;
    const int b    = blockIdx.y;
    const int ti   = blockIdx.x >> 3;   // 32-px tile in i
    const int tj   = blockIdx.x & 7;    // 32-px tile in j
    float* wlds = &lds[wv*1136];

    const float eps8 = epsv[b] * 0.125f;   // 0.25(idct)*0.5(noisy_round)
    const float RT   = 0.70710678118654752f;

    // ---- stage-1 task mapping (branchless 1-idct issue) ----
    const int  xc   = lane & 7;
    const int  q1   = (lane >> 3) & 3;     // Y block for lanes 0-31
    const int  cq   = (lane >> 3) & 1;     // chroma ch for lanes 32-47 (48-63 dup)
    const bool isY1 = lane < 32;

    const int bi  = ti*4 + (wv & 1)*2 + (q1 >> 1);
    const int bj  = tj*4 + (wv >> 1)*2 + (q1 & 1);
    const int ngY = bi*32 + bj;
    const int ngC = (ti*2 + (wv & 1))*16 + (tj*2 + (wv >> 1));

    // ---- issue rv + table loads FIRST ----
    const float* rbase = isY1 ? (rvy + ((size_t)b*1024 + ngY)*64)
                              : ((cq ? rvcr : rvcb) + ((size_t)b*256 + ngC)*64);
    const float4 v0 = *(const float4*)(rbase + xc*8);
    const float4 v1 = *(const float4*)(rbase + xc*8 + 4);
    const float* tb = isY1 ? YBT : CBTc;
    const float4 t0 = *(const float4*)(tb + xc*8);
    const float4 t1 = *(const float4*)(tb + xc*8 + 4);

    // ---- pixel loads second (consumed after stage-1 idct) ----
    const int pi = (lane & 3)*4;
    const int pj = lane >> 2;
    const size_t pb = (size_t)b*196608
                    + (size_t)(tj*32 + (wv >> 1)*16 + pj)*256
                    + (size_t)(ti*32 + (wv & 1)*16 + pi);
    const float4 rP = *(const float4*)(pix + pb);
    const float4 gP = *(const float4*)(pix + pb + 65536);
    const float4 bP = *(const float4*)(pix + pb + 131072);

    // ---- stage 1: column IDCT of scaled noise ----
    {
        const float aax = (xc == 0 ? RT : 1.0f) * eps8;
        float t[8], o[8];
        t[0] = v0.x * (t0.x * aax * RT);   // alpha_y on y=0
        t[1] = v0.y * (t0.y * aax);
        t[2] = v0.z * (t0.z * aax);
        t[3] = v0.w * (t0.w * aax);
        t[4] = v1.x * (t1.x * aax);
        t[5] = v1.y * (t1.y * aax);
        t[6] = v1.z * (t1.z * aax);
        t[7] = v1.w * (t1.w * aax);
        idct8(t, o);
        if (lane < 48) {
            float* w = wlds + (isY1 ? q1*104 : 416 + cq*104) + xc;
            #pragma unroll
            for (int v = 0; v < 8; ++v) w[v*12] = o[v];
        }
    }

    // ---- YCC + chroma 2x2 pool (intra-wave shuffles) ----
    const float rr[4] = {rP.x, rP.y, rP.z, rP.w};
    const float gg[4] = {gP.x, gP.y, gP.z, gP.w};
    const float bb[4] = {bP.x, bP.y, bP.z, bP.w};
    float yv[4], cbv[4], crv[4];
    #pragma unroll
    for (int c = 0; c < 4; ++c) {
        yv[c]  = fmaf(0.299f, rr[c], fmaf(0.587f, gg[c], 0.114f*bb[c]));
        cbv[c] = fmaf(-0.168736f, rr[c], fmaf(-0.331264f, gg[c], 0.5f*bb[c]));
        crv[c] = fmaf(0.5f, rr[c], fmaf(-0.418688f, gg[c], -0.081312f*bb[c]));
    }
    float cb01 = cbv[0] + cbv[1], cb23 = cbv[2] + cbv[3];
    float cr01 = crv[0] + crv[1], cr23 = crv[2] + crv[3];
    cb01 += __shfl_xor(cb01, 4);   // partner row pj^1 (pj bit0 = lane bit2)
    cb23 += __shfl_xor(cb23, 4);
    cr01 += __shfl_xor(cr01, 4);
    cr23 += __shfl_xor(cr23, 4);
    if (!(lane & 4)) {             // even pj: centered pooled chroma (no +128)
        const int cj = pj >> 1, ci = pi >> 1;
        *(f2v*)(wlds + 944  + cj*12 + ci) = (f2v){0.25f*cb01, 0.25f*cb23};
        *(f2v*)(wlds + 1040 + cj*12 + ci) = (f2v){0.25f*cr01, 0.25f*cr23};
    }

    // ---- stage 2: row IDCT (wave-internal LDS RAW, no barrier) ----
    {
        const int v2 = lane & 7;
        const float* rs = wlds + (isY1 ? q1*104 : 416 + cq*104) + v2*12;
        const f4v lo = *(const f4v*)rs;
        const f4v hi = *(const f4v*)(rs + 4);
        float t[8] = {lo.x, lo.y, lo.z, lo.w, hi.x, hi.y, hi.z, hi.w};
        float o[8];
        idct8(t, o);
        if (isY1) {                // Y noise -> ny[j][i]
            float* w = wlds + 624 + ((q1 & 1)*8 + v2)*20 + (q1 >> 1)*8;
            *(f4v*)w       = (f4v){o[0], o[1], o[2], o[3]};
            *(f4v*)(w + 4) = (f4v){o[4], o[5], o[6], o[7]};
        } else if (lane < 48) {    // chroma noise: add into pool row cj=v2
            float* pp = wlds + 944 + cq*96 + v2*12;
            f4v p0 = *(f4v*)pp, p1 = *(f4v*)(pp + 4);
            p0 += (f4v){o[0], o[1], o[2], o[3]};
            p1 += (f4v){o[4], o[5], o[6], o[7]};
            *(f4v*)pp       = p0;
            *(f4v*)(pp + 4) = p1;
        }
    }

    // ---- final: recombine, YCC->RGB, clip, store ----
    const f4v yn4 = *(const f4v*)(wlds + 624 + pj*20 + pi);
    const int cjf = pj >> 1, cif = pi >> 1;
    const f2v cbp = *(const f2v*)(wlds + 944  + cjf*12 + cif);
    const f2v crp = *(const f2v*)(wlds + 1040 + cjf*12 + cif);
    const float yn[4]  = {yn4.x, yn4.y, yn4.z, yn4.w};
    const float cbf[4] = {cbp.x, cbp.x, cbp.y, cbp.y};
    const float crf[4] = {crp.x, crp.x, crp.y, crp.y};
    float ro[4], go[4], bo[4];
    #pragma unroll
    for (int c = 0; c < 4; ++c) {
        const float yf = yv[c] + yn[c];
        float r_ = fmaf(1.402f, crf[c], yf);
        float g_ = fmaf(-0.344136f, cbf[c], fmaf(-0.714136f, crf[c], yf));
        float b_ = fmaf(1.772f, cbf[c], yf);
        ro[c] = fminf(fmaxf(r_, 0.0f), 255.0f);
        go[c] = fminf(fmaxf(g_, 0.0f), 255.0f);
        bo[c] = fminf(fmaxf(b_, 0.0f), 255.0f);
    }
    *(float4*)(out + pb)          = make_float4(ro[0], ro[1], ro[2], ro[3]);
    *(float4*)(out + pb + 65536)  = make_float4(go[0], go[1], go[2], go[3]);
    *(float4*)(out + pb + 131072) = make_float4(bo[0], bo[1], bo[2], bo[3]);
}

extern "C" void kernel_launch(void* const* d_in, const int* in_sizes, int n_in,
                              void* d_out, int out_size, void* d_ws, size_t ws_size,
                              hipStream_t stream) {
    const float* pix  = (const float*)d_in[0];
    const float* rvy  = (const float*)d_in[1];
    const float* rvcb = (const float*)d_in[2];
    const float* rvcr = (const float*)d_in[3];
    const float* eps  = (const float*)d_in[4];
    const int B = in_sizes[4];           // epsilon: one per batch
    dim3 grid(64, B);                    // 8x8 tiles of 32x32 px (16x16/wave)
    jpeg_kernel<<<grid, 256, 0, stream>>>(pix, rvy, rvcb, rvcr, eps, (float*)d_out);
}